// Round 4
// baseline (2144.109 us; speedup 1.0000x reference)
//
#include <hip/hip_runtime.h>

typedef __attribute__((ext_vector_type(8))) short bf16x8;
typedef __attribute__((ext_vector_type(4))) float f32x4;

__device__ __forceinline__ short f2bf(float f) {
  union { float f; unsigned u; } v; v.f = f;
  unsigned r = (v.u + 0x7fffu + ((v.u >> 16) & 1u)) >> 16;
  return (short)r;
}
__device__ __forceinline__ float bf2f(short s) {
  union { unsigned u; float f; } v; v.u = ((unsigned)(unsigned short)s) << 16;
  return v.f;
}
__device__ __forceinline__ float sigmf(float x) { return 1.f / (1.f + __expf(-x)); }
__device__ __forceinline__ float rcpf(float x) { return __builtin_amdgcn_rcpf(x); }
__device__ __forceinline__ float sigmf_fast(float x) { return rcpf(1.f + __expf(-x)); }
__device__ __forceinline__ float tanhf_fast(float x) {
  float e = __expf(-2.f * fabsf(x));          // e in (0,1] -> no overflow
  float r = (1.f - e) * rcpf(1.f + e);
  return copysignf(r, x);
}

// sc0 dword load: L1-bypass, served by the XCD-shared L2 (fresh for same-XCD writers)
__device__ __forceinline__ int ld_sc0(const int* p) {
  int v;
  asm volatile("global_load_dword %0, %1, off sc0\n\ts_waitcnt vmcnt(0)"
               : "=v"(v) : "v"(p) : "memory");
  return v;
}
#define ALOAD(p)     __hip_atomic_load((p), __ATOMIC_RELAXED, __HIP_MEMORY_SCOPE_AGENT)
#define ASTORE(p, v) __hip_atomic_store((p), (v), __ATOMIC_RELAXED, __HIP_MEMORY_SCOPE_AGENT)

// raw barrier: LDS-ordering only — no block-wide vmcnt drain. In-flight global
// loads (xg MALL reads) ride across; compiler's dataflow waitcnt still guards
// their consumption. (verified in r3: 2270 -> 1715us)
__device__ __forceinline__ void bar_lds() {
  __builtin_amdgcn_sched_barrier(0);
  asm volatile("s_waitcnt lgkmcnt(0)" ::: "memory");
  __builtin_amdgcn_s_barrier();
  __builtin_amdgcn_sched_barrier(0);
}
// full per-wave vmem drain + scheduling fence
__device__ __forceinline__ void drain_vm() {
  asm volatile("s_waitcnt vmcnt(0)" ::: "memory");
  __builtin_amdgcn_sched_barrier(0);
}

__device__ __forceinline__ void stage_row_f32(const float* __restrict__ src, short* dst,
                                              int kb, int k0, int K) {
  if (kb + k0 + 15 < K) {
    const f32x4* p4 = (const f32x4*)src;
#pragma unroll
    for (int g = 0; g < 4; g++) {
      f32x4 v = p4[g];
      dst[g * 4 + 0] = f2bf(v.x); dst[g * 4 + 1] = f2bf(v.y);
      dst[g * 4 + 2] = f2bf(v.z); dst[g * 4 + 3] = f2bf(v.w);
    }
  } else {
#pragma unroll
    for (int j = 0; j < 16; j++) {
      float v = (kb + k0 + j < K) ? src[j] : 0.f;
      dst[j] = f2bf(v);
    }
  }
}

// Input projection: relu(A @ W^T + b). Unchanged (verified).
__global__ __launch_bounds__(256) void proj_gemm(
    const float* __restrict__ A, int lda,
    const float* __restrict__ W, int ldw,
    const float* __restrict__ bias,
    short* __restrict__ C, int coloff, int K) {
  __shared__ short As[128][40];
  __shared__ short Bs[128][40];
  const int tid = threadIdx.x;
  const int m0 = blockIdx.x << 7, n0 = blockIdx.y << 7;
  const int w = tid >> 6, lane = tid & 63, m16 = lane & 15, q = lane >> 4;
  const f32x4 vzero = {0.f, 0.f, 0.f, 0.f};
  f32x4 acc[2][8];
#pragma unroll
  for (int mt = 0; mt < 2; mt++)
#pragma unroll
    for (int nt = 0; nt < 8; nt++) acc[mt][nt] = vzero;

  const int nk = (K + 31) >> 5;
  const int r = tid >> 1, k0 = (tid & 1) << 4;
  for (int kc = 0; kc < nk; kc++) {
    const int kb = kc << 5;
    {
      const int gr = m0 + r;
      const size_t arow = (size_t)(gr & 31) * 256 + (size_t)(gr >> 5);
      stage_row_f32(A + arow * (size_t)lda + kb + k0, &As[r][k0], kb, k0, K);
    }
    {
      const float* bp = W + (size_t)(n0 + r) * ldw + kb + k0;
      stage_row_f32(bp, &Bs[r][k0], kb, k0, K);
    }
    __syncthreads();
    bf16x8 af[2], bfv[8];
#pragma unroll
    for (int mt = 0; mt < 2; mt++)
      af[mt] = *(const bf16x8*)&As[(w << 5) + (mt << 4) + m16][q << 3];
#pragma unroll
    for (int nt = 0; nt < 8; nt++)
      bfv[nt] = *(const bf16x8*)&Bs[(nt << 4) + m16][q << 3];
#pragma unroll
    for (int mt = 0; mt < 2; mt++)
#pragma unroll
      for (int nt = 0; nt < 8; nt++)
        acc[mt][nt] = __builtin_amdgcn_mfma_f32_16x16x32_bf16(af[mt], bfv[nt], acc[mt][nt], 0, 0, 0);
    __syncthreads();
  }
#pragma unroll
  for (int mt = 0; mt < 2; mt++)
#pragma unroll
    for (int nt = 0; nt < 8; nt++)
#pragma unroll
      for (int i = 0; i < 4; i++) {
        const int grow = m0 + (w << 5) + (mt << 4) + (q << 2) + i;
        const int gcol = n0 + (nt << 4) + m16;
        float v = fmaxf(acc[mt][nt][i] + bias[gcol], 0.f);
        const int col = coloff + gcol;
        const int tt = grow >> 5, b = grow & 31;
        C[(((size_t)tt * 32 + (col >> 5)) * 32 + b) * 32 + (col & 31)] = f2bf(v);
      }
}

// ============================================================================
// Persistent fused kernel — r3-verified protocol (1715us gru), plus two
// isolated h-chain deltas:
//   (d) register-path publish: gates pack h pairs via __shfl_xor; EVERY dword
//       of the chunk gets a plain store (even lane -> local L2) AND an sc1
//       store (odd lane -> MALL mirror) — same dual-visibility bytes as the
//       old hout+wave-3-mirror path, but no hout LDS round-trip, no SYNC-B,
//       and the mirror is spread across all waves instead of a wave-3 serial
//       tail. One drained barrier then sets lflag+mir (same ordering
//       guarantees as the old SYNC-C + drained wave-3 flag).
//   (e) per-wave producer-subset flag wait: wave w's MFMA only consumes ranks
//       8w..8w+7, so it polls only those 8 flags; SYNC-A still joins waves.
//       A straggler rank now only delays the wave that reads it.
// Latch/mirror fallback, farm, ring protocol: identical to verified r3.
// ============================================================================
__global__ __launch_bounds__(256, 1) void gru_giant(
    const float* __restrict__ Whh_f, const float* __restrict__ Whh_b,
    const float* __restrict__ Wih_f, const float* __restrict__ Wih_b,
    const float* __restrict__ bih_f, const float* __restrict__ bhh_f,
    const float* __restrict__ bih_b, const float* __restrict__ bhh_b,
    const short* __restrict__ x0c, short* __restrict__ ybase,
    short* __restrict__ ringbase, int* __restrict__ ctrl) {
  const int gid = blockIdx.x & 7;
  const int r = blockIdx.x >> 3;
  const int tid = threadIdx.x;
  const int w = tid >> 6, lane = tid & 63, m16 = lane & 15, q = lane >> 4;

  __shared__ float hgp[4 * 96 * 33];  // [wave][row=gate*32+dd][col=b(+pad)]
  __shared__ int smode[2];            // [0]=mirror latch, [1]=fr/bp cache

  const int hgrp = (gid < 4) ? gid : (gid - 4);
  const int layer = hgrp >> 1, chain = hgrp & 1;
  const size_t WL = (size_t)3072 * 1024;
  const float* Wsl = ((gid < 4) ? (chain ? Whh_b : Whh_f)
                                : (chain ? Wih_b : Wih_f)) + layer * WL;

  // ---- preload weight slice as A-frags (96 rows x 1024, fp32->bf16) ----
  const int d0 = r << 5;
  const int kw = w << 8;
  bf16x8 a[6][8];
#pragma unroll
  for (int mt = 0; mt < 6; mt++) {
    const int row = (mt >> 1) * 1024 + d0 + ((mt & 1) << 4) + m16;
#pragma unroll
    for (int ks = 0; ks < 8; ks++) {
      const int kk = kw + ks * 32 + (q << 3);
      const f32x4* wp = (const f32x4*)(Wsl + (size_t)row * 1024 + kk);
      f32x4 lo = wp[0], hi = wp[1];
      bf16x8 t;
      t[0] = f2bf(lo.x); t[1] = f2bf(lo.y); t[2] = f2bf(lo.z); t[3] = f2bf(lo.w);
      t[4] = f2bf(hi.x); t[5] = f2bf(hi.y); t[6] = f2bf(hi.z); t[7] = f2bf(hi.w);
      a[mt][ks] = t;
    }
  }

  // ---- rendezvous (removes preload skew so local-poll bounds are honest) ----
  if (tid == 0) {
    (void)__hip_atomic_fetch_add(ctrl + 400, 1, __ATOMIC_RELAXED, __HIP_MEMORY_SCOPE_AGENT);
    smode[0] = 0; smode[1] = 0;
  }
  if (w == 0) {
    while (ALOAD(ctrl + 400) < 256) __builtin_amdgcn_s_sleep(4);
  }
  __syncthreads();

  int* lflag = ctrl + hgrp * 32;
  int* mir   = ctrl + 128 + hgrp * 32;
  int* fr    = ctrl + 256 + hgrp * 32;
  short* y    = ybase + (size_t)hgrp * 8388608;
  short* ring = ringbase + (size_t)hgrp * 3145728;
  const f32x4 vz = {0.f, 0.f, 0.f, 0.f};

  if (gid < 4) {
    // ================= h-chain block =================
    const float* bih = (chain ? bih_b : bih_f) + layer * 3072;
    const float* bhh = (chain ? bhh_b : bhh_f) + layer * 3072;
    const int dd = tid & 31, bq = tid >> 5;
    const int dg = d0 + dd;
    const float Cr = bih[dg] + bhh[dg];
    const float Cz = bih[1024 + dg] + bhh[1024 + dg];
    const float bni = bih[2048 + dg], bnh = bhh[2048 + dg];
    float h[4] = {0.f, 0.f, 0.f, 0.f};

    for (int t = 0; t < 256; t++) {
      // ---- farm flag FIRST (cached; farm runs ahead so this rarely polls) ----
      if (smode[1] < t + 1) {
        for (;;) {
          int v = ALOAD(fr + r);
          if (v >= t + 1) { smode[1] = v; break; }
          __builtin_amdgcn_s_sleep(1);
        }
      }
      // ---- xg pre-loads issued BEFORE the flag wait (MALL latency overlaps
      //      the poll; agent scope: ring slots are address-reused) ----
      unsigned xgv[12];
      {
        const short* cb = ring + ((size_t)(t & 31) * 32 + r) * 3072;
#pragma unroll
        for (int k2 = 0; k2 < 4; k2++) {
          const int b = bq + (k2 << 3);
#pragma unroll
          for (int gate = 0; gate < 3; gate++)
            xgv[k2 * 3 + gate] =
                ALOAD((const unsigned*)(cb + (gate * 32 + b) * 32 + (dd & ~1)));
        }
      }
      // ---- producer-subset flag wait: wave w needs only ranks 8w..8w+7 ----
      if (t > 0) {
        if (smode[0] == 0) {
          bool ok = false;
          for (int it = 0; it < 256; it++) {
            int v = ld_sc0(lflag + (w << 3) + (lane & 7));
            if (__all(v >= t)) { ok = true; break; }
            if (it > 8) __builtin_amdgcn_s_sleep(1);
          }
          if (!ok) smode[0] = 1;  // latch to MALL mirror (benign LDS race)
        }
        if (smode[0]) {
          for (;;) {
            int v = ALOAD(mir + (lane & 31));
            if (__all(v >= t)) break;
            __builtin_amdgcn_s_sleep(1);
          }
        }
      }
      // ---- h-part MFMA on y[t-1] (plain cached loads; first-touch per line) ----
      f32x4 acc[6][2];
#pragma unroll
      for (int mt = 0; mt < 6; mt++) { acc[mt][0] = vz; acc[mt][1] = vz; }
      if (t > 0) {
        const short* yc = y + (size_t)(t - 1) * 32768;
        bf16x8 bfr[2][8];
#pragma unroll
        for (int nt = 0; nt < 2; nt++) {
          const int n = (nt << 4) + m16;
#pragma unroll
          for (int ks = 0; ks < 8; ks++) {
            const int gk = (w << 3) + ks;
            bfr[nt][ks] = *(const bf16x8*)(yc + (size_t)gk * 1024 + n * 32 + (q << 3));
          }
        }
#pragma unroll
        for (int ks = 0; ks < 8; ks++)
#pragma unroll
          for (int mt = 0; mt < 6; mt++)
#pragma unroll
            for (int nt = 0; nt < 2; nt++)
              acc[mt][nt] = __builtin_amdgcn_mfma_f32_16x16x32_bf16(a[mt][ks], bfr[nt][ks], acc[mt][nt], 0, 0, 0);
      }
#pragma unroll
      for (int mt = 0; mt < 6; mt++)
#pragma unroll
        for (int nt = 0; nt < 2; nt++)
#pragma unroll
          for (int i = 0; i < 4; i++)
            hgp[((size_t)w * 96 + mt * 16 + (q << 2) + i) * 33 + (nt << 4) + m16] = acc[mt][nt][i];
      bar_lds();                                            // SYNC-A (lgkm-only)

      // ---- gates (fast math) + lane-pair pack ----
      unsigned hw[4];
#pragma unroll
      for (int k2 = 0; k2 < 4; k2++) {
        const int b = bq + (k2 << 3);
        float hr = 0.f, hz = 0.f, hn = 0.f;
#pragma unroll
        for (int ww = 0; ww < 4; ww++) {
          hr += hgp[((size_t)ww * 96 + dd) * 33 + b];
          hz += hgp[((size_t)ww * 96 + 32 + dd) * 33 + b];
          hn += hgp[((size_t)ww * 96 + 64 + dd) * 33 + b];
        }
        const unsigned ur = xgv[k2 * 3 + 0], uz = xgv[k2 * 3 + 1], un = xgv[k2 * 3 + 2];
        const int hi = dd & 1;
        const float xr = bf2f((short)(hi ? (ur >> 16) : (ur & 0xFFFF)));
        const float xz = bf2f((short)(hi ? (uz >> 16) : (uz & 0xFFFF)));
        const float xn = bf2f((short)(hi ? (un >> 16) : (un & 0xFFFF)));
        const float rr = sigmf_fast(xr + Cr + hr);
        const float zz = sigmf_fast(xz + Cz + hz);
        const float nn = tanhf_fast(xn + bni + rr * (hn + bnh));
        h[k2] = (1.f - zz) * nn + zz * h[k2];
        // pack (dim dd&~1, dim dd|1) into one dword; both lanes of the pair
        // end up holding the identical dword for dword index (b, dd>>1)
        unsigned mine = (unsigned)(unsigned short)f2bf(h[k2]);
        unsigned oth  = (unsigned)__shfl_xor((int)mine, 1) & 0xFFFFu;
        hw[k2] = (dd & 1) ? ((mine << 16) | oth) : ((oth << 16) | mine);
      }

      // ---- publish + mirror, register path (replaces hout/SYNC-B/SYNC-C and
      //      the wave-3 serial mirror): every dword gets a plain store (even
      //      lane, local L2) AND an sc1 store (odd lane, MALL) — same dual
      //      visibility as before ----
      {
        unsigned* cbase = (unsigned*)(y + ((size_t)t * 32 + r) * 1024);
#pragma unroll
        for (int k2 = 0; k2 < 4; k2++) {
          const int b = bq + (k2 << 3);
          unsigned* dp = cbase + b * 16 + (dd >> 1);
          if (dd & 1) ASTORE(dp, hw[k2]);   // agent/sc1: through to MALL
          else        *dp = hw[k2];         // plain: local L2 for same-XCD readers
        }
      }
      drain_vm();                       // per-wave: all publish+mirror stores done
      __builtin_amdgcn_s_barrier();     // every wave drained -> chunk fully visible
      if (tid == 0) {
        *(volatile int*)(lflag + r) = t + 1;   // local flag (L2)
        ASTORE(mir + r, t + 1);                // MALL flag (after all sc1 stores)
      }
    }
  } else {
    // ================= farm block: xg[t] = Wih_slice @ src[t], 2 steps/iter ====
    const short* src = (layer == 0) ? x0c : (ybase + (size_t)chain * 8388608);
    const int* srcmir = (layer == 0) ? nullptr : (ctrl + 128 + chain * 32);
    for (int t = 0; t < 256; t += 2) {
      if (srcmir) {  // need src[t], src[t+1]
        for (;;) {
          int v = ALOAD(srcmir + (lane & 31));
          if (__all(v >= t + 2)) break;
          __builtin_amdgcn_s_sleep(1);
        }
      }
      if (t >= 24 && smode[1] < t - 22) {  // ring backpressure vs consumer rank r
        for (;;) {
          int v = ALOAD(mir + r);
          if (v >= t - 22) { smode[1] = v; break; }
          __builtin_amdgcn_s_sleep(1);
        }
      }
      f32x4 acc0[6][2], acc1[6][2];
#pragma unroll
      for (int mt = 0; mt < 6; mt++) {
        acc0[mt][0] = vz; acc0[mt][1] = vz; acc1[mt][0] = vz; acc1[mt][1] = vz;
      }
#pragma unroll
      for (int half = 0; half < 2; half++) {
        const short* sc = src + (size_t)(t + half) * 32768;
        bf16x8 bfr[2][8];
#pragma unroll
        for (int nt = 0; nt < 2; nt++) {
          const int n = (nt << 4) + m16;
#pragma unroll
          for (int ks = 0; ks < 8; ks++) {
            const int gk = (w << 3) + ks;
            bfr[nt][ks] = *(const bf16x8*)(sc + (size_t)gk * 1024 + n * 32 + (q << 3));
          }
        }
#pragma unroll
        for (int ks = 0; ks < 8; ks++)
#pragma unroll
          for (int mt = 0; mt < 6; mt++)
#pragma unroll
            for (int nt = 0; nt < 2; nt++) {
              if (half == 0)
                acc0[mt][nt] = __builtin_amdgcn_mfma_f32_16x16x32_bf16(a[mt][ks], bfr[nt][ks], acc0[mt][nt], 0, 0, 0);
              else
                acc1[mt][nt] = __builtin_amdgcn_mfma_f32_16x16x32_bf16(a[mt][ks], bfr[nt][ks], acc1[mt][nt], 0, 0, 0);
            }
      }
#pragma unroll
      for (int half = 0; half < 2; half++) {
#pragma unroll
        for (int mt = 0; mt < 6; mt++)
#pragma unroll
          for (int nt = 0; nt < 2; nt++)
#pragma unroll
            for (int i = 0; i < 4; i++)
              hgp[((size_t)w * 96 + mt * 16 + (q << 2) + i) * 33 + (nt << 4) + m16] =
                  (half == 0) ? acc0[mt][nt][i] : acc1[mt][nt][i];
        __syncthreads();
        if (tid < 192) {  // 4-wave reduce + pack + sc1 store of 6KB chunk
          const int l0 = tid << 4;
          const int gate = l0 >> 10, b = (l0 >> 5) & 31, dd0 = l0 & 31;
          short tmp[16];
#pragma unroll
          for (int j = 0; j < 16; j++) {
            float s = 0.f;
#pragma unroll
            for (int ww = 0; ww < 4; ww++)
              s += hgp[((size_t)ww * 96 + gate * 32 + dd0 + j) * 33 + b];
            tmp[j] = f2bf(s);
          }
          unsigned long long* dp = (unsigned long long*)(
              ring + ((size_t)((t + half) & 31) * 32 + r) * 3072 + l0);
          const unsigned long long* sp = (const unsigned long long*)tmp;
#pragma unroll
          for (int j = 0; j < 4; j++) ASTORE(dp + j, sp[j]);
        }
        __syncthreads();  // implicit drain; also guards hgp overwrite
      }
      if (tid == 0) ASTORE(fr + r, t + 2);
    }
  }
}

// y1 chunk-32 layout: elem(row=t*32+b, c) at ((t*32 + (c>>5))*32 + b)*32 + (c&31)
__global__ __launch_bounds__(256) void final_dot(
    const short* __restrict__ yF, const short* __restrict__ yB,
    const float* __restrict__ Wo, const float* __restrict__ bo,
    float* __restrict__ partials) {
  const int w = threadIdx.x >> 6, lane = threadIdx.x & 63;
  __shared__ float red[4];
  float acc = 0.f;
  const int r0 = (blockIdx.x << 7) + (w << 5);
  for (int rr = 0; rr < 32; rr++) {
    const int r = r0 + rr;
    const size_t rbase = (size_t)(r >> 5) * 32768 + (size_t)(r & 31) * 32;
    float s = 0.f;
    for (int c = lane; c < 1024; c += 64) {
      const size_t idx = rbase + (size_t)(c >> 5) * 1024 + (c & 31);
      s += (bf2f(yF[idx]) + bf2f(yB[idx])) * Wo[c];
    }
#pragma unroll
    for (int off = 32; off > 0; off >>= 1) s += __shfl_down(s, off);
    if (lane == 0) acc += sigmf(s + bo[0]);
  }
  if (lane == 0) red[w] = acc;
  __syncthreads();
  if (threadIdx.x == 0) partials[blockIdx.x] = red[0] + red[1] + red[2] + red[3];
}

__global__ void final_reduce(const float* __restrict__ partials, float* __restrict__ out) {
  float s = partials[threadIdx.x];
#pragma unroll
  for (int off = 32; off > 0; off >>= 1) s += __shfl_down(s, off);
  if (threadIdx.x == 0) out[0] = s * (1.f / 8192.f);
}

extern "C" void kernel_launch(void* const* d_in, const int* in_sizes, int n_in,
                              void* d_out, int out_size, void* d_ws, size_t ws_size,
                              hipStream_t stream) {
  const float* in_x  = (const float*)d_in[0];   // [32,256,72]
  const float* in_c  = (const float*)d_in[1];   // [32,256,80]
  const float* Wc    = (const float*)d_in[2];   // [512,80]
  const float* bc    = (const float*)d_in[3];
  const float* Wi    = (const float*)d_in[4];   // [512,72]
  const float* bi    = (const float*)d_in[5];
  const float* Wih_f = (const float*)d_in[6];   // [2,3072,1024]
  const float* Whh_f = (const float*)d_in[7];
  const float* bih_f = (const float*)d_in[8];
  const float* bhh_f = (const float*)d_in[9];
  const float* Wih_b = (const float*)d_in[10];
  const float* Whh_b = (const float*)d_in[11];
  const float* bih_b = (const float*)d_in[12];
  const float* bhh_b = (const float*)d_in[13];
  const float* Wo    = (const float*)d_in[14];  // [1,1024]
  const float* bo    = (const float*)d_in[15];
  float* out = (float*)d_out;

  char* base = (char*)d_ws;
  const size_t SX = (size_t)8192 * 1024 * 2;        // 16.78 MB x0 chunk buffer
  const size_t SY = (size_t)8192 * 1024 * 2;        // per y buffer
  const size_t SR = (size_t)32 * 32 * 3072 * 2;     // 6.29 MB per xg ring
  short* x0c  = (short*)(base);
  short* ybase = (short*)(base + SX);               // 4 buffers (L0f,L0b,L1f,L1b)
  short* ringbase = (short*)(base + SX + 4 * SY);   // 4 rings
  float* partials = (float*)(base + SX + 4 * SY + 4 * SR);
  int* ctrl = (int*)(base + SX + 4 * SY + 4 * SR + 4096);
  // total ws use ~109 MB

  hipMemsetAsync(ctrl, 0, 2048, stream);

  dim3 blk(256);
  proj_gemm<<<dim3(64, 4), blk, 0, stream>>>(in_c, 80, Wc, 80, bc, x0c, 0, 80);
  proj_gemm<<<dim3(64, 4), blk, 0, stream>>>(in_x, 72, Wi, 72, bi, x0c, 512, 72);
  gru_giant<<<dim3(256), blk, 0, stream>>>(Whh_f, Whh_b, Wih_f, Wih_b,
                                           bih_f, bhh_f, bih_b, bhh_b,
                                           x0c, ybase, ringbase, ctrl);
  short* y1f = ybase + (size_t)2 * 8388608;
  short* y1b = ybase + (size_t)3 * 8388608;
  final_dot<<<dim3(64), blk, 0, stream>>>(y1f, y1b, Wo, bo, partials);
  final_reduce<<<dim3(1), dim3(64), 0, stream>>>(partials, out);
}

// Round 5
// 1832.748 us; speedup vs baseline: 1.1699x; 1.1699x over previous
//
#include <hip/hip_runtime.h>

typedef __attribute__((ext_vector_type(8))) short bf16x8;
typedef __attribute__((ext_vector_type(4))) float f32x4;

__device__ __forceinline__ short f2bf(float f) {
  union { float f; unsigned u; } v; v.f = f;
  unsigned r = (v.u + 0x7fffu + ((v.u >> 16) & 1u)) >> 16;
  return (short)r;
}
__device__ __forceinline__ float bf2f(short s) {
  union { unsigned u; float f; } v; v.u = ((unsigned)(unsigned short)s) << 16;
  return v.f;
}
__device__ __forceinline__ float sigmf(float x) { return 1.f / (1.f + __expf(-x)); }
__device__ __forceinline__ float rcpf(float x) { return __builtin_amdgcn_rcpf(x); }
__device__ __forceinline__ float sigmf_fast(float x) { return rcpf(1.f + __expf(-x)); }
__device__ __forceinline__ float tanhf_fast(float x) {
  float e = __expf(-2.f * fabsf(x));          // e in (0,1] -> no overflow
  float r = (1.f - e) * rcpf(1.f + e);
  return copysignf(r, x);
}

// sc0 dword load: L1-bypass, served by the XCD-shared L2 (fresh for same-XCD writers)
__device__ __forceinline__ int ld_sc0(const int* p) {
  int v;
  asm volatile("global_load_dword %0, %1, off sc0\n\ts_waitcnt vmcnt(0)"
               : "=v"(v) : "v"(p) : "memory");
  return v;
}
#define ALOAD(p)     __hip_atomic_load((p), __ATOMIC_RELAXED, __HIP_MEMORY_SCOPE_AGENT)
#define ASTORE(p, v) __hip_atomic_store((p), (v), __ATOMIC_RELAXED, __HIP_MEMORY_SCOPE_AGENT)

// raw barrier: LDS-ordering only — no block-wide vmcnt drain. In-flight global
// loads (xg MALL reads) ride across; compiler's dataflow waitcnt still guards
// their consumption. (verified in r3: 2270 -> 1715us)
__device__ __forceinline__ void bar_lds() {
  __builtin_amdgcn_sched_barrier(0);
  asm volatile("s_waitcnt lgkmcnt(0)" ::: "memory");
  __builtin_amdgcn_s_barrier();
  __builtin_amdgcn_sched_barrier(0);
}

__device__ __forceinline__ void stage_row_f32(const float* __restrict__ src, short* dst,
                                              int kb, int k0, int K) {
  if (kb + k0 + 15 < K) {
    const f32x4* p4 = (const f32x4*)src;
#pragma unroll
    for (int g = 0; g < 4; g++) {
      f32x4 v = p4[g];
      dst[g * 4 + 0] = f2bf(v.x); dst[g * 4 + 1] = f2bf(v.y);
      dst[g * 4 + 2] = f2bf(v.z); dst[g * 4 + 3] = f2bf(v.w);
    }
  } else {
#pragma unroll
    for (int j = 0; j < 16; j++) {
      float v = (kb + k0 + j < K) ? src[j] : 0.f;
      dst[j] = f2bf(v);
    }
  }
}

// Input projection: relu(A @ W^T + b). Unchanged (verified).
__global__ __launch_bounds__(256) void proj_gemm(
    const float* __restrict__ A, int lda,
    const float* __restrict__ W, int ldw,
    const float* __restrict__ bias,
    short* __restrict__ C, int coloff, int K) {
  __shared__ short As[128][40];
  __shared__ short Bs[128][40];
  const int tid = threadIdx.x;
  const int m0 = blockIdx.x << 7, n0 = blockIdx.y << 7;
  const int w = tid >> 6, lane = tid & 63, m16 = lane & 15, q = lane >> 4;
  const f32x4 vzero = {0.f, 0.f, 0.f, 0.f};
  f32x4 acc[2][8];
#pragma unroll
  for (int mt = 0; mt < 2; mt++)
#pragma unroll
    for (int nt = 0; nt < 8; nt++) acc[mt][nt] = vzero;

  const int nk = (K + 31) >> 5;
  const int r = tid >> 1, k0 = (tid & 1) << 4;
  for (int kc = 0; kc < nk; kc++) {
    const int kb = kc << 5;
    {
      const int gr = m0 + r;
      const size_t arow = (size_t)(gr & 31) * 256 + (size_t)(gr >> 5);
      stage_row_f32(A + arow * (size_t)lda + kb + k0, &As[r][k0], kb, k0, K);
    }
    {
      const float* bp = W + (size_t)(n0 + r) * ldw + kb + k0;
      stage_row_f32(bp, &Bs[r][k0], kb, k0, K);
    }
    __syncthreads();
    bf16x8 af[2], bfv[8];
#pragma unroll
    for (int mt = 0; mt < 2; mt++)
      af[mt] = *(const bf16x8*)&As[(w << 5) + (mt << 4) + m16][q << 3];
#pragma unroll
    for (int nt = 0; nt < 8; nt++)
      bfv[nt] = *(const bf16x8*)&Bs[(nt << 4) + m16][q << 3];
#pragma unroll
    for (int mt = 0; mt < 2; mt++)
#pragma unroll
      for (int nt = 0; nt < 8; nt++)
        acc[mt][nt] = __builtin_amdgcn_mfma_f32_16x16x32_bf16(af[mt], bfv[nt], acc[mt][nt], 0, 0, 0);
    __syncthreads();
  }
#pragma unroll
  for (int mt = 0; mt < 2; mt++)
#pragma unroll
    for (int nt = 0; nt < 8; nt++)
#pragma unroll
      for (int i = 0; i < 4; i++) {
        const int grow = m0 + (w << 5) + (mt << 4) + (q << 2) + i;
        const int gcol = n0 + (nt << 4) + m16;
        float v = fmaxf(acc[mt][nt][i] + bias[gcol], 0.f);
        const int col = coloff + gcol;
        const int tt = grow >> 5, b = grow & 31;
        C[(((size_t)tt * 32 + (col >> 5)) * 32 + b) * 32 + (col & 31)] = f2bf(v);
      }
}

// ============================================================================
// Persistent fused kernel — r3-verified structure (gru 1715us: lgkm-only
// SYNC-A/B, xg hoist, fast gates, hout publish + wave-3 mirror), plus ONE
// isolated delta:
//   (e) producer-subset flag wait: wave w's MFMA only consumes ranks
//       8w..8w+7, so it polls only those 8 lflags (instead of all 32).
//       SYNC-A still joins waves, so correctness is unchanged; a straggler
//       rank now only delays the one wave that reads its chunk, and the
//       other waves' y-loads/MFMA overlap the straggler's publish.
// r4's register-path publish (d) REVERTED: it put the sc1 MALL store-ack on
// every wave's per-step critical path (gru 1715 -> 1975us). The r3 path keeps
// that drain on wave 3 only, overlapped with the next step's flag polls.
// ============================================================================
__global__ __launch_bounds__(256, 1) void gru_giant(
    const float* __restrict__ Whh_f, const float* __restrict__ Whh_b,
    const float* __restrict__ Wih_f, const float* __restrict__ Wih_b,
    const float* __restrict__ bih_f, const float* __restrict__ bhh_f,
    const float* __restrict__ bih_b, const float* __restrict__ bhh_b,
    const short* __restrict__ x0c, short* __restrict__ ybase,
    short* __restrict__ ringbase, int* __restrict__ ctrl) {
  const int gid = blockIdx.x & 7;
  const int r = blockIdx.x >> 3;
  const int tid = threadIdx.x;
  const int w = tid >> 6, lane = tid & 63, m16 = lane & 15, q = lane >> 4;

  __shared__ float hgp[4 * 96 * 33];  // [wave][row=gate*32+dd][col=b(+pad)]
  __shared__ short hout[32 * 40];
  __shared__ int smode[2];            // [0]=mirror latch, [1]=fr/bp cache

  const int hgrp = (gid < 4) ? gid : (gid - 4);
  const int layer = hgrp >> 1, chain = hgrp & 1;
  const size_t WL = (size_t)3072 * 1024;
  const float* Wsl = ((gid < 4) ? (chain ? Whh_b : Whh_f)
                                : (chain ? Wih_b : Wih_f)) + layer * WL;

  // ---- preload weight slice as A-frags (96 rows x 1024, fp32->bf16) ----
  const int d0 = r << 5;
  const int kw = w << 8;
  bf16x8 a[6][8];
#pragma unroll
  for (int mt = 0; mt < 6; mt++) {
    const int row = (mt >> 1) * 1024 + d0 + ((mt & 1) << 4) + m16;
#pragma unroll
    for (int ks = 0; ks < 8; ks++) {
      const int kk = kw + ks * 32 + (q << 3);
      const f32x4* wp = (const f32x4*)(Wsl + (size_t)row * 1024 + kk);
      f32x4 lo = wp[0], hi = wp[1];
      bf16x8 t;
      t[0] = f2bf(lo.x); t[1] = f2bf(lo.y); t[2] = f2bf(lo.z); t[3] = f2bf(lo.w);
      t[4] = f2bf(hi.x); t[5] = f2bf(hi.y); t[6] = f2bf(hi.z); t[7] = f2bf(hi.w);
      a[mt][ks] = t;
    }
  }

  // ---- rendezvous (removes preload skew so local-poll bounds are honest) ----
  if (tid == 0) {
    (void)__hip_atomic_fetch_add(ctrl + 400, 1, __ATOMIC_RELAXED, __HIP_MEMORY_SCOPE_AGENT);
    smode[0] = 0; smode[1] = 0;
  }
  if (w == 0) {
    while (ALOAD(ctrl + 400) < 256) __builtin_amdgcn_s_sleep(4);
  }
  __syncthreads();

  int* lflag = ctrl + hgrp * 32;
  int* mir   = ctrl + 128 + hgrp * 32;
  int* fr    = ctrl + 256 + hgrp * 32;
  short* y    = ybase + (size_t)hgrp * 8388608;
  short* ring = ringbase + (size_t)hgrp * 3145728;
  const f32x4 vz = {0.f, 0.f, 0.f, 0.f};

  if (gid < 4) {
    // ================= h-chain block =================
    const float* bih = (chain ? bih_b : bih_f) + layer * 3072;
    const float* bhh = (chain ? bhh_b : bhh_f) + layer * 3072;
    const int dd = tid & 31, bq = tid >> 5;
    const int dg = d0 + dd;
    const float Cr = bih[dg] + bhh[dg];
    const float Cz = bih[1024 + dg] + bhh[1024 + dg];
    const float bni = bih[2048 + dg], bnh = bhh[2048 + dg];
    float h[4] = {0.f, 0.f, 0.f, 0.f};

    for (int t = 0; t < 256; t++) {
      // ---- farm flag FIRST (cached; farm runs ahead so this rarely polls) ----
      if (smode[1] < t + 1) {
        for (;;) {
          int v = ALOAD(fr + r);
          if (v >= t + 1) { smode[1] = v; break; }
          __builtin_amdgcn_s_sleep(1);
        }
      }
      // ---- xg pre-loads issued BEFORE the flag wait (MALL latency overlaps
      //      the poll; agent scope: ring slots are address-reused) ----
      unsigned xgv[12];
      {
        const short* cb = ring + ((size_t)(t & 31) * 32 + r) * 3072;
#pragma unroll
        for (int k2 = 0; k2 < 4; k2++) {
          const int b = bq + (k2 << 3);
#pragma unroll
          for (int gate = 0; gate < 3; gate++)
            xgv[k2 * 3 + gate] =
                ALOAD((const unsigned*)(cb + (gate * 32 + b) * 32 + (dd & ~1)));
        }
      }
      // ---- (e) producer-subset flag wait: wave w needs only ranks 8w..8w+7 ----
      if (t > 0) {
        if (smode[0] == 0) {
          bool ok = false;
          for (int it = 0; it < 256; it++) {
            int v = ld_sc0(lflag + (w << 3) + (lane & 7));
            if (__all(v >= t)) { ok = true; break; }
            if (it > 8) __builtin_amdgcn_s_sleep(1);
          }
          if (!ok) smode[0] = 1;  // latch to MALL mirror (benign LDS race)
        }
        if (smode[0]) {
          for (;;) {
            int v = ALOAD(mir + (lane & 31));
            if (__all(v >= t)) break;
            __builtin_amdgcn_s_sleep(1);
          }
        }
      }
      // ---- h-part MFMA on y[t-1] (plain cached loads; first-touch per line) ----
      f32x4 acc[6][2];
#pragma unroll
      for (int mt = 0; mt < 6; mt++) { acc[mt][0] = vz; acc[mt][1] = vz; }
      if (t > 0) {
        const short* yc = y + (size_t)(t - 1) * 32768;
        bf16x8 bfr[2][8];
#pragma unroll
        for (int nt = 0; nt < 2; nt++) {
          const int n = (nt << 4) + m16;
#pragma unroll
          for (int ks = 0; ks < 8; ks++) {
            const int gk = (w << 3) + ks;
            bfr[nt][ks] = *(const bf16x8*)(yc + (size_t)gk * 1024 + n * 32 + (q << 3));
          }
        }
#pragma unroll
        for (int ks = 0; ks < 8; ks++)
#pragma unroll
          for (int mt = 0; mt < 6; mt++)
#pragma unroll
            for (int nt = 0; nt < 2; nt++)
              acc[mt][nt] = __builtin_amdgcn_mfma_f32_16x16x32_bf16(a[mt][ks], bfr[nt][ks], acc[mt][nt], 0, 0, 0);
      }
#pragma unroll
      for (int mt = 0; mt < 6; mt++)
#pragma unroll
        for (int nt = 0; nt < 2; nt++)
#pragma unroll
          for (int i = 0; i < 4; i++)
            hgp[((size_t)w * 96 + mt * 16 + (q << 2) + i) * 33 + (nt << 4) + m16] = acc[mt][nt][i];
      bar_lds();                                            // SYNC-A (lgkm-only)

      // ---- gates (fast math; xg waits are compiler dataflow waits) ----
#pragma unroll
      for (int k2 = 0; k2 < 4; k2++) {
        const int b = bq + (k2 << 3);
        float hr = 0.f, hz = 0.f, hn = 0.f;
#pragma unroll
        for (int ww = 0; ww < 4; ww++) {
          hr += hgp[((size_t)ww * 96 + dd) * 33 + b];
          hz += hgp[((size_t)ww * 96 + 32 + dd) * 33 + b];
          hn += hgp[((size_t)ww * 96 + 64 + dd) * 33 + b];
        }
        const unsigned ur = xgv[k2 * 3 + 0], uz = xgv[k2 * 3 + 1], un = xgv[k2 * 3 + 2];
        const int hi = dd & 1;
        const float xr = bf2f((short)(hi ? (ur >> 16) : (ur & 0xFFFF)));
        const float xz = bf2f((short)(hi ? (uz >> 16) : (uz & 0xFFFF)));
        const float xn = bf2f((short)(hi ? (un >> 16) : (un & 0xFFFF)));
        const float rr = sigmf_fast(xr + Cr + hr);
        const float zz = sigmf_fast(xz + Cz + hz);
        const float nn = tanhf_fast(xn + bni + rr * (hn + bnh));
        h[k2] = (1.f - zz) * nn + zz * h[k2];
        hout[b * 40 + dd] = f2bf(h[k2]);
      }
      bar_lds();                                            // SYNC-B (lgkm-only)

      // ---- publish chunk (t, r): plain (local L2) ----
      {
        const int b = tid >> 3, c = (tid & 7) << 2;
        *(unsigned long long*)(y + ((size_t)t * 32 + r) * 1024 + b * 32 + c) =
            *(const unsigned long long*)&hout[b * 40 + c];
      }
      __syncthreads();  // SYNC-C: implicit per-wave vmcnt drain -> chunk in local L2
      if (tid == 0) *(volatile int*)(lflag + r) = t + 1;  // local flag
      // ---- unconditional MALL mirror (wave 3): sc1 copy + drained sc1 flag ----
      if (w == 3) {
        const int b2 = lane >> 1, dl0 = (lane & 1) << 4;
        const unsigned long long* sp = (const unsigned long long*)&hout[b2 * 40 + dl0];
        unsigned long long* dp =
            (unsigned long long*)(y + ((size_t)t * 32 + r) * 1024 + b2 * 32 + dl0);
#pragma unroll
        for (int j = 0; j < 4; j++) ASTORE(dp + j, sp[j]);
        asm volatile("s_waitcnt vmcnt(0)" ::: "memory");
        if (lane == 0) ASTORE(mir + r, t + 1);
      }
    }
  } else {
    // ================= farm block: xg[t] = Wih_slice @ src[t], 2 steps/iter ====
    const short* src = (layer == 0) ? x0c : (ybase + (size_t)chain * 8388608);
    const int* srcmir = (layer == 0) ? nullptr : (ctrl + 128 + chain * 32);
    for (int t = 0; t < 256; t += 2) {
      if (srcmir) {  // need src[t], src[t+1]
        for (;;) {
          int v = ALOAD(srcmir + (lane & 31));
          if (__all(v >= t + 2)) break;
          __builtin_amdgcn_s_sleep(1);
        }
      }
      if (t >= 24 && smode[1] < t - 22) {  // ring backpressure vs consumer rank r
        for (;;) {
          int v = ALOAD(mir + r);
          if (v >= t - 22) { smode[1] = v; break; }
          __builtin_amdgcn_s_sleep(1);
        }
      }
      f32x4 acc0[6][2], acc1[6][2];
#pragma unroll
      for (int mt = 0; mt < 6; mt++) {
        acc0[mt][0] = vz; acc0[mt][1] = vz; acc1[mt][0] = vz; acc1[mt][1] = vz;
      }
#pragma unroll
      for (int half = 0; half < 2; half++) {
        const short* sc = src + (size_t)(t + half) * 32768;
        bf16x8 bfr[2][8];
#pragma unroll
        for (int nt = 0; nt < 2; nt++) {
          const int n = (nt << 4) + m16;
#pragma unroll
          for (int ks = 0; ks < 8; ks++) {
            const int gk = (w << 3) + ks;
            bfr[nt][ks] = *(const bf16x8*)(sc + (size_t)gk * 1024 + n * 32 + (q << 3));
          }
        }
#pragma unroll
        for (int ks = 0; ks < 8; ks++)
#pragma unroll
          for (int mt = 0; mt < 6; mt++)
#pragma unroll
            for (int nt = 0; nt < 2; nt++) {
              if (half == 0)
                acc0[mt][nt] = __builtin_amdgcn_mfma_f32_16x16x32_bf16(a[mt][ks], bfr[nt][ks], acc0[mt][nt], 0, 0, 0);
              else
                acc1[mt][nt] = __builtin_amdgcn_mfma_f32_16x16x32_bf16(a[mt][ks], bfr[nt][ks], acc1[mt][nt], 0, 0, 0);
            }
      }
#pragma unroll
      for (int half = 0; half < 2; half++) {
#pragma unroll
        for (int mt = 0; mt < 6; mt++)
#pragma unroll
          for (int nt = 0; nt < 2; nt++)
#pragma unroll
            for (int i = 0; i < 4; i++)
              hgp[((size_t)w * 96 + mt * 16 + (q << 2) + i) * 33 + (nt << 4) + m16] =
                  (half == 0) ? acc0[mt][nt][i] : acc1[mt][nt][i];
        __syncthreads();
        if (tid < 192) {  // 4-wave reduce + pack + sc1 store of 6KB chunk
          const int l0 = tid << 4;
          const int gate = l0 >> 10, b = (l0 >> 5) & 31, dd0 = l0 & 31;
          short tmp[16];
#pragma unroll
          for (int j = 0; j < 16; j++) {
            float s = 0.f;
#pragma unroll
            for (int ww = 0; ww < 4; ww++)
              s += hgp[((size_t)ww * 96 + gate * 32 + dd0 + j) * 33 + b];
            tmp[j] = f2bf(s);
          }
          unsigned long long* dp = (unsigned long long*)(
              ring + ((size_t)((t + half) & 31) * 32 + r) * 3072 + l0);
          const unsigned long long* sp = (const unsigned long long*)tmp;
#pragma unroll
          for (int j = 0; j < 4; j++) ASTORE(dp + j, sp[j]);
        }
        __syncthreads();  // implicit drain; also guards hgp overwrite
      }
      if (tid == 0) ASTORE(fr + r, t + 2);
    }
  }
}

// y1 chunk-32 layout: elem(row=t*32+b, c) at ((t*32 + (c>>5))*32 + b)*32 + (c&31)
__global__ __launch_bounds__(256) void final_dot(
    const short* __restrict__ yF, const short* __restrict__ yB,
    const float* __restrict__ Wo, const float* __restrict__ bo,
    float* __restrict__ partials) {
  const int w = threadIdx.x >> 6, lane = threadIdx.x & 63;
  __shared__ float red[4];
  float acc = 0.f;
  const int r0 = (blockIdx.x << 7) + (w << 5);
  for (int rr = 0; rr < 32; rr++) {
    const int r = r0 + rr;
    const size_t rbase = (size_t)(r >> 5) * 32768 + (size_t)(r & 31) * 32;
    float s = 0.f;
    for (int c = lane; c < 1024; c += 64) {
      const size_t idx = rbase + (size_t)(c >> 5) * 1024 + (c & 31);
      s += (bf2f(yF[idx]) + bf2f(yB[idx])) * Wo[c];
    }
#pragma unroll
    for (int off = 32; off > 0; off >>= 1) s += __shfl_down(s, off);
    if (lane == 0) acc += sigmf(s + bo[0]);
  }
  if (lane == 0) red[w] = acc;
  __syncthreads();
  if (threadIdx.x == 0) partials[blockIdx.x] = red[0] + red[1] + red[2] + red[3];
}

__global__ void final_reduce(const float* __restrict__ partials, float* __restrict__ out) {
  float s = partials[threadIdx.x];
#pragma unroll
  for (int off = 32; off > 0; off >>= 1) s += __shfl_down(s, off);
  if (threadIdx.x == 0) out[0] = s * (1.f / 8192.f);
}

extern "C" void kernel_launch(void* const* d_in, const int* in_sizes, int n_in,
                              void* d_out, int out_size, void* d_ws, size_t ws_size,
                              hipStream_t stream) {
  const float* in_x  = (const float*)d_in[0];   // [32,256,72]
  const float* in_c  = (const float*)d_in[1];   // [32,256,80]
  const float* Wc    = (const float*)d_in[2];   // [512,80]
  const float* bc    = (const float*)d_in[3];
  const float* Wi    = (const float*)d_in[4];   // [512,72]
  const float* bi    = (const float*)d_in[5];
  const float* Wih_f = (const float*)d_in[6];   // [2,3072,1024]
  const float* Whh_f = (const float*)d_in[7];
  const float* bih_f = (const float*)d_in[8];
  const float* bhh_f = (const float*)d_in[9];
  const float* Wih_b = (const float*)d_in[10];
  const float* Whh_b = (const float*)d_in[11];
  const float* bih_b = (const float*)d_in[12];
  const float* bhh_b = (const float*)d_in[13];
  const float* Wo    = (const float*)d_in[14];  // [1,1024]
  const float* bo    = (const float*)d_in[15];
  float* out = (float*)d_out;

  char* base = (char*)d_ws;
  const size_t SX = (size_t)8192 * 1024 * 2;        // 16.78 MB x0 chunk buffer
  const size_t SY = (size_t)8192 * 1024 * 2;        // per y buffer
  const size_t SR = (size_t)32 * 32 * 3072 * 2;     // 6.29 MB per xg ring
  short* x0c  = (short*)(base);
  short* ybase = (short*)(base + SX);               // 4 buffers (L0f,L0b,L1f,L1b)
  short* ringbase = (short*)(base + SX + 4 * SY);   // 4 rings
  float* partials = (float*)(base + SX + 4 * SY + 4 * SR);
  int* ctrl = (int*)(base + SX + 4 * SY + 4 * SR + 4096);
  // total ws use ~109 MB

  hipMemsetAsync(ctrl, 0, 2048, stream);

  dim3 blk(256);
  proj_gemm<<<dim3(64, 4), blk, 0, stream>>>(in_c, 80, Wc, 80, bc, x0c, 0, 80);
  proj_gemm<<<dim3(64, 4), blk, 0, stream>>>(in_x, 72, Wi, 72, bi, x0c, 512, 72);
  gru_giant<<<dim3(256), blk, 0, stream>>>(Whh_f, Whh_b, Wih_f, Wih_b,
                                           bih_f, bhh_f, bih_b, bhh_b,
                                           x0c, ybase, ringbase, ctrl);
  short* y1f = ybase + (size_t)2 * 8388608;
  short* y1b = ybase + (size_t)3 * 8388608;
  final_dot<<<dim3(64), blk, 0, stream>>>(y1f, y1b, Wo, bo, partials);
  final_reduce<<<dim3(1), dim3(64), 0, stream>>>(partials, out);
}

// Round 7
// 1829.973 us; speedup vs baseline: 1.1717x; 1.0015x over previous
//
#include <hip/hip_runtime.h>

typedef __attribute__((ext_vector_type(8))) short bf16x8;
typedef __attribute__((ext_vector_type(4))) float f32x4;

__device__ __forceinline__ short f2bf(float f) {
  union { float f; unsigned u; } v; v.f = f;
  unsigned r = (v.u + 0x7fffu + ((v.u >> 16) & 1u)) >> 16;
  return (short)r;
}
__device__ __forceinline__ float bf2f(short s) {
  union { unsigned u; float f; } v; v.u = ((unsigned)(unsigned short)s) << 16;
  return v.f;
}
__device__ __forceinline__ float sigmf(float x) { return 1.f / (1.f + __expf(-x)); }
__device__ __forceinline__ float rcpf(float x) { return __builtin_amdgcn_rcpf(x); }
__device__ __forceinline__ float sigmf_fast(float x) { return rcpf(1.f + __expf(-x)); }
__device__ __forceinline__ float tanhf_fast(float x) {
  float e = __expf(-2.f * fabsf(x));          // e in (0,1] -> no overflow
  float r = (1.f - e) * rcpf(1.f + e);
  return copysignf(r, x);
}

// sc0 dword load: L1-bypass, served by the XCD-shared L2 (fresh for same-XCD
// writers). NOTE: the trailing vmcnt(0) drains ALL outstanding vmem of the
// calling wave — (h) exploits this to absorb the deferred mirror drain.
__device__ __forceinline__ int ld_sc0(const int* p) {
  int v;
  asm volatile("global_load_dword %0, %1, off sc0\n\ts_waitcnt vmcnt(0)"
               : "=v"(v) : "v"(p) : "memory");
  return v;
}
#define ALOAD(p)     __hip_atomic_load((p), __ATOMIC_RELAXED, __HIP_MEMORY_SCOPE_AGENT)
#define ASTORE(p, v) __hip_atomic_store((p), (v), __ATOMIC_RELAXED, __HIP_MEMORY_SCOPE_AGENT)

// raw barrier: LDS-ordering only — no block-wide vmcnt drain. In-flight global
// loads (xg MALL reads) ride across; compiler's dataflow waitcnt still guards
// their consumption. (verified r3: 2270 -> 1715us)
__device__ __forceinline__ void bar_lds() {
  __builtin_amdgcn_sched_barrier(0);
  asm volatile("s_waitcnt lgkmcnt(0)" ::: "memory");
  __builtin_amdgcn_s_barrier();
  __builtin_amdgcn_sched_barrier(0);
}
// full per-wave vmem drain + scheduling fence
__device__ __forceinline__ void drain_vm() {
  asm volatile("s_waitcnt vmcnt(0)" ::: "memory");
  __builtin_amdgcn_sched_barrier(0);
}

__device__ __forceinline__ void stage_row_f32(const float* __restrict__ src, short* dst,
                                              int kb, int k0, int K) {
  if (kb + k0 + 15 < K) {
    const f32x4* p4 = (const f32x4*)src;
#pragma unroll
    for (int g = 0; g < 4; g++) {
      f32x4 v = p4[g];
      dst[g * 4 + 0] = f2bf(v.x); dst[g * 4 + 1] = f2bf(v.y);
      dst[g * 4 + 2] = f2bf(v.z); dst[g * 4 + 3] = f2bf(v.w);
    }
  } else {
#pragma unroll
    for (int j = 0; j < 16; j++) {
      float v = (kb + k0 + j < K) ? src[j] : 0.f;
      dst[j] = f2bf(v);
    }
  }
}

// Input projection: relu(A @ W^T + b). Unchanged (verified).
__global__ __launch_bounds__(256) void proj_gemm(
    const float* __restrict__ A, int lda,
    const float* __restrict__ W, int ldw,
    const float* __restrict__ bias,
    short* __restrict__ C, int coloff, int K) {
  __shared__ short As[128][40];
  __shared__ short Bs[128][40];
  const int tid = threadIdx.x;
  const int m0 = blockIdx.x << 7, n0 = blockIdx.y << 7;
  const int w = tid >> 6, lane = tid & 63, m16 = lane & 15, q = lane >> 4;
  const f32x4 vzero = {0.f, 0.f, 0.f, 0.f};
  f32x4 acc[2][8];
#pragma unroll
  for (int mt = 0; mt < 2; mt++)
#pragma unroll
    for (int nt = 0; nt < 8; nt++) acc[mt][nt] = vzero;

  const int nk = (K + 31) >> 5;
  const int r = tid >> 1, k0 = (tid & 1) << 4;
  for (int kc = 0; kc < nk; kc++) {
    const int kb = kc << 5;
    {
      const int gr = m0 + r;
      const size_t arow = (size_t)(gr & 31) * 256 + (size_t)(gr >> 5);
      stage_row_f32(A + arow * (size_t)lda + kb + k0, &As[r][k0], kb, k0, K);
    }
    {
      const float* bp = W + (size_t)(n0 + r) * ldw + kb + k0;
      stage_row_f32(bp, &Bs[r][k0], kb, k0, K);
    }
    __syncthreads();
    bf16x8 af[2], bfv[8];
#pragma unroll
    for (int mt = 0; mt < 2; mt++)
      af[mt] = *(const bf16x8*)&As[(w << 5) + (mt << 4) + m16][q << 3];
#pragma unroll
    for (int nt = 0; nt < 8; nt++)
      bfv[nt] = *(const bf16x8*)&Bs[(nt << 4) + m16][q << 3];
#pragma unroll
    for (int mt = 0; mt < 2; mt++)
#pragma unroll
      for (int nt = 0; nt < 8; nt++)
        acc[mt][nt] = __builtin_amdgcn_mfma_f32_16x16x32_bf16(af[mt], bfv[nt], acc[mt][nt], 0, 0, 0);
    __syncthreads();
  }
#pragma unroll
  for (int mt = 0; mt < 2; mt++)
#pragma unroll
    for (int nt = 0; nt < 8; nt++)
#pragma unroll
      for (int i = 0; i < 4; i++) {
        const int grow = m0 + (w << 5) + (mt << 4) + (q << 2) + i;
        const int gcol = n0 + (nt << 4) + m16;
        float v = fmaxf(acc[mt][nt][i] + bias[gcol], 0.f);
        const int col = coloff + gcol;
        const int tt = grow >> 5, b = grow & 31;
        C[(((size_t)tt * 32 + (col >> 5)) * 32 + b) * 32 + (col & 31)] = f2bf(v);
      }
}

// ============================================================================
// Persistent fused kernel — r5-verified structure (gru 1628us) + deltas:
//   (f) direct register publish: gates store h (2B plain stores) straight to
//       y; hout kept ONLY as wave-3 mirror source; SYNC-B deleted.
//   (g) load reorder for FIFO vmcnt: flag wait FIRST (polls drain only flag
//       dwords); then y loads, THEN xg loads — MFMA's compiler wait is
//       counted (leaves xg in flight), xg completes under MFMA+SYNC-A.
//   (h) deferred mirror drain: wave 3 issues sc1 mirror stores undrained; the
//       next step's ld_sc0 poll (vmcnt(0)) absorbs the drain, then lane 0
//       publishes mir = t. Post-loop drain publishes mir = 256.
//       DEADLOCK FIX vs r6: in the latched (all-MALL) path, wave 3 drains and
//       publishes mir = t BEFORE entering the mir wait — under all-latch the
//       old order (publish after wait) was a circular wait.
// Farm blocks, ring protocol, latch fallback: identical to verified r5.
// ============================================================================
__global__ __launch_bounds__(256, 1) void gru_giant(
    const float* __restrict__ Whh_f, const float* __restrict__ Whh_b,
    const float* __restrict__ Wih_f, const float* __restrict__ Wih_b,
    const float* __restrict__ bih_f, const float* __restrict__ bhh_f,
    const float* __restrict__ bih_b, const float* __restrict__ bhh_b,
    const short* __restrict__ x0c, short* __restrict__ ybase,
    short* __restrict__ ringbase, int* __restrict__ ctrl) {
  const int gid = blockIdx.x & 7;
  const int r = blockIdx.x >> 3;
  const int tid = threadIdx.x;
  const int w = tid >> 6, lane = tid & 63, m16 = lane & 15, q = lane >> 4;

  __shared__ float hgp[4 * 96 * 33];  // [wave][row=gate*32+dd][col=b(+pad)]
  __shared__ short hout[32 * 40];     // mirror source only (f)
  __shared__ int smode[2];            // [0]=mirror latch, [1]=fr/bp cache

  const int hgrp = (gid < 4) ? gid : (gid - 4);
  const int layer = hgrp >> 1, chain = hgrp & 1;
  const size_t WL = (size_t)3072 * 1024;
  const float* Wsl = ((gid < 4) ? (chain ? Whh_b : Whh_f)
                                : (chain ? Wih_b : Wih_f)) + layer * WL;

  // ---- preload weight slice as A-frags (96 rows x 1024, fp32->bf16) ----
  const int d0 = r << 5;
  const int kw = w << 8;
  bf16x8 a[6][8];
#pragma unroll
  for (int mt = 0; mt < 6; mt++) {
    const int row = (mt >> 1) * 1024 + d0 + ((mt & 1) << 4) + m16;
#pragma unroll
    for (int ks = 0; ks < 8; ks++) {
      const int kk = kw + ks * 32 + (q << 3);
      const f32x4* wp = (const f32x4*)(Wsl + (size_t)row * 1024 + kk);
      f32x4 lo = wp[0], hi = wp[1];
      bf16x8 t;
      t[0] = f2bf(lo.x); t[1] = f2bf(lo.y); t[2] = f2bf(lo.z); t[3] = f2bf(lo.w);
      t[4] = f2bf(hi.x); t[5] = f2bf(hi.y); t[6] = f2bf(hi.z); t[7] = f2bf(hi.w);
      a[mt][ks] = t;
    }
  }

  // ---- rendezvous (removes preload skew so local-poll bounds are honest) ----
  if (tid == 0) {
    (void)__hip_atomic_fetch_add(ctrl + 400, 1, __ATOMIC_RELAXED, __HIP_MEMORY_SCOPE_AGENT);
    smode[0] = 0; smode[1] = 0;
  }
  if (w == 0) {
    while (ALOAD(ctrl + 400) < 256) __builtin_amdgcn_s_sleep(4);
  }
  __syncthreads();

  int* lflag = ctrl + hgrp * 32;
  int* mir   = ctrl + 128 + hgrp * 32;
  int* fr    = ctrl + 256 + hgrp * 32;
  short* y    = ybase + (size_t)hgrp * 8388608;
  short* ring = ringbase + (size_t)hgrp * 3145728;
  const f32x4 vz = {0.f, 0.f, 0.f, 0.f};

  if (gid < 4) {
    // ================= h-chain block =================
    const float* bih = (chain ? bih_b : bih_f) + layer * 3072;
    const float* bhh = (chain ? bhh_b : bhh_f) + layer * 3072;
    const int dd = tid & 31, bq = tid >> 5;
    const int dg = d0 + dd;
    const float Cr = bih[dg] + bhh[dg];
    const float Cz = bih[1024 + dg] + bhh[1024 + dg];
    const float bni = bih[2048 + dg], bnh = bhh[2048 + dg];
    float h[4] = {0.f, 0.f, 0.f, 0.f};

    for (int t = 0; t < 256; t++) {
      // ---- farm flag (cached; farm runs ahead so this rarely polls) ----
      if (smode[1] < t + 1) {
        for (;;) {
          int v = ALOAD(fr + r);
          if (v >= t + 1) { smode[1] = v; break; }
          __builtin_amdgcn_s_sleep(1);
        }
      }
      // ---- (e) producer-subset flag wait FIRST (g): polls drain only their
      //      own flag dwords now ----
      if (t > 0) {
        if (smode[0] == 0) {
          bool ok = false;
          for (int it = 0; it < 256; it++) {
            int v = ld_sc0(lflag + (w << 3) + (lane & 7));
            if (__all(v >= t)) { ok = true; break; }
            if (it > 8) __builtin_amdgcn_s_sleep(1);
          }
          if (!ok) smode[0] = 1;  // latch to MALL mirror (benign LDS race)
        }
        if (smode[0]) {
          // (h)+FIX: drain + publish BEFORE the wait — under all-latch the
          // publish-after-wait order is a circular wait (deadlock).
          if (w == 3) {
            drain_vm();
            if (lane == 0) ASTORE(mir + r, t);
          }
          for (;;) {
            int v = ALOAD(mir + (lane & 31));
            if (__all(v >= t)) break;
            __builtin_amdgcn_s_sleep(1);
          }
        } else {
          // hot path: the ld_sc0 polls above (vmcnt(0)) already drained
          // wave-3's step t-1 mirror stores
          if (w == 3 && lane == 0) ASTORE(mir + r, t);
        }
      }
      // ---- y[t-1] frag loads ISSUED BEFORE xg (FIFO vmcnt: MFMA's wait is
      //      counted, leaving xg in flight) ----
      bf16x8 bfr[2][8];
      if (t > 0) {
        const short* yc = y + (size_t)(t - 1) * 32768;
#pragma unroll
        for (int nt = 0; nt < 2; nt++) {
          const int n = (nt << 4) + m16;
#pragma unroll
          for (int ks = 0; ks < 8; ks++) {
            const int gk = (w << 3) + ks;
            bfr[nt][ks] = *(const bf16x8*)(yc + (size_t)gk * 1024 + n * 32 + (q << 3));
          }
        }
      }
      // ---- xg loads SECOND (g): fly across MFMA + SYNC-A, consumed at gates
      //      (agent scope: ring slots are address-reused -> bypass caches) ----
      unsigned xgv[12];
      {
        const short* cb = ring + ((size_t)(t & 31) * 32 + r) * 3072;
#pragma unroll
        for (int k2 = 0; k2 < 4; k2++) {
          const int b = bq + (k2 << 3);
#pragma unroll
          for (int gate = 0; gate < 3; gate++)
            xgv[k2 * 3 + gate] =
                ALOAD((const unsigned*)(cb + (gate * 32 + b) * 32 + (dd & ~1)));
        }
      }
      // ---- h-part MFMA on y[t-1] ----
      f32x4 acc[6][2];
#pragma unroll
      for (int mt = 0; mt < 6; mt++) { acc[mt][0] = vz; acc[mt][1] = vz; }
      if (t > 0) {
#pragma unroll
        for (int ks = 0; ks < 8; ks++)
#pragma unroll
          for (int mt = 0; mt < 6; mt++)
#pragma unroll
            for (int nt = 0; nt < 2; nt++)
              acc[mt][nt] = __builtin_amdgcn_mfma_f32_16x16x32_bf16(a[mt][ks], bfr[nt][ks], acc[mt][nt], 0, 0, 0);
      }
#pragma unroll
      for (int mt = 0; mt < 6; mt++)
#pragma unroll
        for (int nt = 0; nt < 2; nt++)
#pragma unroll
          for (int i = 0; i < 4; i++)
            hgp[((size_t)w * 96 + mt * 16 + (q << 2) + i) * 33 + (nt << 4) + m16] = acc[mt][nt][i];
      bar_lds();                                            // SYNC-A (lgkm-only)

      // ---- gates (fast math) + (f) direct register publish ----
      short* ychunk = y + ((size_t)t * 32 + r) * 1024;
#pragma unroll
      for (int k2 = 0; k2 < 4; k2++) {
        const int b = bq + (k2 << 3);
        float hr = 0.f, hz = 0.f, hn = 0.f;
#pragma unroll
        for (int ww = 0; ww < 4; ww++) {
          hr += hgp[((size_t)ww * 96 + dd) * 33 + b];
          hz += hgp[((size_t)ww * 96 + 32 + dd) * 33 + b];
          hn += hgp[((size_t)ww * 96 + 64 + dd) * 33 + b];
        }
        const unsigned ur = xgv[k2 * 3 + 0], uz = xgv[k2 * 3 + 1], un = xgv[k2 * 3 + 2];
        const int hi = dd & 1;
        const float xr = bf2f((short)(hi ? (ur >> 16) : (ur & 0xFFFF)));
        const float xz = bf2f((short)(hi ? (uz >> 16) : (uz & 0xFFFF)));
        const float xn = bf2f((short)(hi ? (un >> 16) : (un & 0xFFFF)));
        const float rr = sigmf_fast(xr + Cr + hr);
        const float zz = sigmf_fast(xz + Cz + hz);
        const float nn = tanhf_fast(xn + bni + rr * (hn + bnh));
        h[k2] = (1.f - zz) * nn + zz * h[k2];
        const short hv = f2bf(h[k2]);
        hout[b * 40 + dd] = hv;        // mirror source (wave 3, after SYNC-C)
        ychunk[b * 32 + dd] = hv;      // plain 2B store -> local L2 (64B/row segs)
      }
      __syncthreads();  // SYNC-C: drains publish stores per-wave; orders hout
      if (tid == 0) *(volatile int*)(lflag + r) = t + 1;  // local flag
      // ---- (h) mirror issue only (wave 3): sc1 copy, NO drain here ----
      if (w == 3) {
        const int b2 = lane >> 1, dl0 = (lane & 1) << 4;
        const unsigned long long* sp = (const unsigned long long*)&hout[b2 * 40 + dl0];
        unsigned long long* dp =
            (unsigned long long*)(y + ((size_t)t * 32 + r) * 1024 + b2 * 32 + dl0);
#pragma unroll
        for (int j = 0; j < 4; j++) ASTORE(dp + j, sp[j]);
      }
    }
    // ---- (h) finalize: drain last mirror, publish mir=256 ----
    drain_vm();
    if (w == 3 && lane == 0) ASTORE(mir + r, 256);
  } else {
    // ================= farm block: xg[t] = Wih_slice @ src[t], 2 steps/iter ====
    const short* src = (layer == 0) ? x0c : (ybase + (size_t)chain * 8388608);
    const int* srcmir = (layer == 0) ? nullptr : (ctrl + 128 + chain * 32);
    for (int t = 0; t < 256; t += 2) {
      if (srcmir) {  // need src[t], src[t+1]
        for (;;) {
          int v = ALOAD(srcmir + (lane & 31));
          if (__all(v >= t + 2)) break;
          __builtin_amdgcn_s_sleep(1);
        }
      }
      if (t >= 24 && smode[1] < t - 22) {  // ring backpressure vs consumer rank r
        for (;;) {
          int v = ALOAD(mir + r);
          if (v >= t - 22) { smode[1] = v; break; }
          __builtin_amdgcn_s_sleep(1);
        }
      }
      f32x4 acc0[6][2], acc1[6][2];
#pragma unroll
      for (int mt = 0; mt < 6; mt++) {
        acc0[mt][0] = vz; acc0[mt][1] = vz; acc1[mt][0] = vz; acc1[mt][1] = vz;
      }
#pragma unroll
      for (int half = 0; half < 2; half++) {
        const short* sc = src + (size_t)(t + half) * 32768;
        bf16x8 bfr[2][8];
#pragma unroll
        for (int nt = 0; nt < 2; nt++) {
          const int n = (nt << 4) + m16;
#pragma unroll
          for (int ks = 0; ks < 8; ks++) {
            const int gk = (w << 3) + ks;
            bfr[nt][ks] = *(const bf16x8*)(sc + (size_t)gk * 1024 + n * 32 + (q << 3));
          }
        }
#pragma unroll
        for (int ks = 0; ks < 8; ks++)
#pragma unroll
          for (int mt = 0; mt < 6; mt++)
#pragma unroll
            for (int nt = 0; nt < 2; nt++) {
              if (half == 0)
                acc0[mt][nt] = __builtin_amdgcn_mfma_f32_16x16x32_bf16(a[mt][ks], bfr[nt][ks], acc0[mt][nt], 0, 0, 0);
              else
                acc1[mt][nt] = __builtin_amdgcn_mfma_f32_16x16x32_bf16(a[mt][ks], bfr[nt][ks], acc1[mt][nt], 0, 0, 0);
            }
      }
#pragma unroll
      for (int half = 0; half < 2; half++) {
#pragma unroll
        for (int mt = 0; mt < 6; mt++)
#pragma unroll
          for (int nt = 0; nt < 2; nt++)
#pragma unroll
            for (int i = 0; i < 4; i++)
              hgp[((size_t)w * 96 + mt * 16 + (q << 2) + i) * 33 + (nt << 4) + m16] =
                  (half == 0) ? acc0[mt][nt][i] : acc1[mt][nt][i];
        __syncthreads();
        if (tid < 192) {  // 4-wave reduce + pack + sc1 store of 6KB chunk
          const int l0 = tid << 4;
          const int gate = l0 >> 10, b = (l0 >> 5) & 31, dd0 = l0 & 31;
          short tmp[16];
#pragma unroll
          for (int j = 0; j < 16; j++) {
            float s = 0.f;
#pragma unroll
            for (int ww = 0; ww < 4; ww++)
              s += hgp[((size_t)ww * 96 + gate * 32 + dd0 + j) * 33 + b];
            tmp[j] = f2bf(s);
          }
          unsigned long long* dp = (unsigned long long*)(
              ring + ((size_t)((t + half) & 31) * 32 + r) * 3072 + l0);
          const unsigned long long* sp = (const unsigned long long*)tmp;
#pragma unroll
          for (int j = 0; j < 4; j++) ASTORE(dp + j, sp[j]);
        }
        __syncthreads();  // implicit drain; also guards hgp overwrite
      }
      if (tid == 0) ASTORE(fr + r, t + 2);
    }
  }
}

// y1 chunk-32 layout: elem(row=t*32+b, c) at ((t*32 + (c>>5))*32 + b)*32 + (c&31)
__global__ __launch_bounds__(256) void final_dot(
    const short* __restrict__ yF, const short* __restrict__ yB,
    const float* __restrict__ Wo, const float* __restrict__ bo,
    float* __restrict__ partials) {
  const int w = threadIdx.x >> 6, lane = threadIdx.x & 63;
  __shared__ float red[4];
  float acc = 0.f;
  const int r0 = (blockIdx.x << 7) + (w << 5);
  for (int rr = 0; rr < 32; rr++) {
    const int r = r0 + rr;
    const size_t rbase = (size_t)(r >> 5) * 32768 + (size_t)(r & 31) * 32;
    float s = 0.f;
    for (int c = lane; c < 1024; c += 64) {
      const size_t idx = rbase + (size_t)(c >> 5) * 1024 + (c & 31);
      s += (bf2f(yF[idx]) + bf2f(yB[idx])) * Wo[c];
    }
#pragma unroll
    for (int off = 32; off > 0; off >>= 1) s += __shfl_down(s, off);
    if (lane == 0) acc += sigmf(s + bo[0]);
  }
  if (lane == 0) red[w] = acc;
  __syncthreads();
  if (threadIdx.x == 0) partials[blockIdx.x] = red[0] + red[1] + red[2] + red[3];
}

__global__ void final_reduce(const float* __restrict__ partials, float* __restrict__ out) {
  float s = partials[threadIdx.x];
#pragma unroll
  for (int off = 32; off > 0; off >>= 1) s += __shfl_down(s, off);
  if (threadIdx.x == 0) out[0] = s * (1.f / 8192.f);
}

extern "C" void kernel_launch(void* const* d_in, const int* in_sizes, int n_in,
                              void* d_out, int out_size, void* d_ws, size_t ws_size,
                              hipStream_t stream) {
  const float* in_x  = (const float*)d_in[0];   // [32,256,72]
  const float* in_c  = (const float*)d_in[1];   // [32,256,80]
  const float* Wc    = (const float*)d_in[2];   // [512,80]
  const float* bc    = (const float*)d_in[3];
  const float* Wi    = (const float*)d_in[4];   // [512,72]
  const float* bi    = (const float*)d_in[5];
  const float* Wih_f = (const float*)d_in[6];   // [2,3072,1024]
  const float* Whh_f = (const float*)d_in[7];
  const float* bih_f = (const float*)d_in[8];
  const float* bhh_f = (const float*)d_in[9];
  const float* Wih_b = (const float*)d_in[10];
  const float* Whh_b = (const float*)d_in[11];
  const float* bih_b = (const float*)d_in[12];
  const float* bhh_b = (const float*)d_in[13];
  const float* Wo    = (const float*)d_in[14];  // [1,1024]
  const float* bo    = (const float*)d_in[15];
  float* out = (float*)d_out;

  char* base = (char*)d_ws;
  const size_t SX = (size_t)8192 * 1024 * 2;        // 16.78 MB x0 chunk buffer
  const size_t SY = (size_t)8192 * 1024 * 2;        // per y buffer
  const size_t SR = (size_t)32 * 32 * 3072 * 2;     // 6.29 MB per xg ring
  short* x0c  = (short*)(base);
  short* ybase = (short*)(base + SX);               // 4 buffers (L0f,L0b,L1f,L1b)
  short* ringbase = (short*)(base + SX + 4 * SY);   // 4 rings
  float* partials = (float*)(base + SX + 4 * SY + 4 * SR);
  int* ctrl = (int*)(base + SX + 4 * SY + 4 * SR + 4096);
  // total ws use ~109 MB

  hipMemsetAsync(ctrl, 0, 2048, stream);

  dim3 blk(256);
  proj_gemm<<<dim3(64, 4), blk, 0, stream>>>(in_c, 80, Wc, 80, bc, x0c, 0, 80);
  proj_gemm<<<dim3(64, 4), blk, 0, stream>>>(in_x, 72, Wi, 72, bi, x0c, 512, 72);
  gru_giant<<<dim3(256), blk, 0, stream>>>(Whh_f, Whh_b, Wih_f, Wih_b,
                                           bih_f, bhh_f, bih_b, bhh_b,
                                           x0c, ybase, ringbase, ctrl);
  short* y1f = ybase + (size_t)2 * 8388608;
  short* y1b = ybase + (size_t)3 * 8388608;
  final_dot<<<dim3(64), blk, 0, stream>>>(y1f, y1b, Wo, bo, partials);
  final_reduce<<<dim3(1), dim3(64), 0, stream>>>(partials, out);
}